// Round 13
// baseline (198.498 us; speedup 1.0000x reference)
//
#include <hip/hip_runtime.h>
#include <hip/hip_fp16.h>
#include <cstdio>

#define B_  64
#define I_  2048
#define J_  16
#define N_  64
#define D_  16
#define K_  1024   // N_*D_

typedef __attribute__((ext_vector_type(2))) float float2v;

#if __has_builtin(__builtin_amdgcn_cvt_pk_u8_f32)
#define CVTPK_U8(f, sel, old) (unsigned)__builtin_amdgcn_cvt_pk_u8_f32((f), (sel), (old))
#else
__device__ __forceinline__ unsigned cvtpk_u8_sw(float f, unsigned sel, unsigned old) {
  unsigned b = (unsigned)(int)f & 0xffu;
  unsigned sh = sel * 8u;
  return (old & ~(0xffu << sh)) | (b << sh);
}
#define CVTPK_U8(f, sel, old) cvtpk_u8_sw((f), (sel), (old))
#endif

// packed f32 FMA with scalar broadcast from src0's lo/hi half (VOP3P op_sel)
__device__ __forceinline__ void pk_fma_lo(float2v& a, float2v x, float2v w) {
  asm("v_pk_fma_f32 %0, %1, %2, %0 op_sel:[0,0,0] op_sel_hi:[0,1,1]"
      : "+v"(a) : "v"(x), "v"(w));
}
__device__ __forceinline__ void pk_fma_hi(float2v& a, float2v x, float2v w) {
  asm("v_pk_fma_f32 %0, %1, %2, %0 op_sel:[1,0,0] op_sel_hi:[1,1,1]"
      : "+v"(a) : "v"(x), "v"(w));
}

// ---------- projection: u_hat u8(biased int8) [b][i][k] + per-(b,i,n) f16 scale ----
// Block = (i, half of b). W[i] k-slice PINNED in regs via asm-opacity (compiler
// cannot rematerialize the loads); 32 v_pk_fma_f32 per b; cvt_pk_u8 quant.
__global__ __launch_bounds__(256, 3) void project_k(const float* __restrict__ x,
                                                    const float* __restrict__ W,
                                                    unsigned char* __restrict__ uh,
                                                    unsigned short* __restrict__ sc) {
  const int i  = blockIdx.x >> 1;
  const int b0 = (blockIdx.x & 1) * 32;
  const int t  = threadIdx.x;

  __shared__ float4 xl4[32 * 4];       // 2 KB: x[b0+bb][i][0..15]
  if (t < 128) {
    int bb = t >> 2, q = t & 3;
    xl4[t] = ((const float4*)(x + ((size_t)(b0 + bb) * I_ + i) * J_))[q];
  }

  const float4* Wp = (const float4*)(W + (size_t)i * (J_ * K_));
  float2v w2[32];                      // 64 VGPR: W[j][k0..k0+3] as 2 pairs per j
#pragma unroll
  for (int j = 0; j < J_; ++j) {
    float4 wv = Wp[j * (K_ / 4) + t];
    w2[2 * j]     = float2v{wv.x, wv.y};
    w2[2 * j + 1] = float2v{wv.z, wv.w};
  }
  // PIN: make w2 opaque so the compiler must keep it live (no remat/reload)
#pragma unroll
  for (int p = 0; p < 32; ++p) asm volatile("" : "+v"(w2[p]));

  __syncthreads();

  unsigned char*  op  = uh + ((size_t)b0 * I_ + i) * K_ + t * 4;
  unsigned short* scp = sc + ((size_t)b0 * I_ + i) * N_ + (t >> 2);
  const bool lead = (t & 3) == 0;
  const float2v* xlp = (const float2v*)xl4;   // 8 j-pairs per b

#define QUANT_STORE(A01, A23) do {                                              \
    float ax_ = fmaxf(fmaxf(fabsf((A01).x), fabsf((A01).y)),                    \
                      fmaxf(fabsf((A23).x), fabsf((A23).y)));                   \
    ax_ = fmaxf(ax_, __shfl_xor(ax_, 1));                                       \
    ax_ = fmaxf(ax_, __shfl_xor(ax_, 2));                                       \
    float inv_ = __fdividef(127.0f, fmaxf(ax_, 1e-30f));                        \
    float e0_ = rintf(fmaf((A01).x, inv_, 128.f));                              \
    float e1_ = rintf(fmaf((A01).y, inv_, 128.f));                              \
    float e2_ = rintf(fmaf((A23).x, inv_, 128.f));                              \
    float e3_ = rintf(fmaf((A23).y, inv_, 128.f));                              \
    unsigned pk_ = CVTPK_U8(e0_, 0u, 0u);                                       \
    pk_ = CVTPK_U8(e1_, 1u, pk_);                                               \
    pk_ = CVTPK_U8(e2_, 2u, pk_);                                               \
    pk_ = CVTPK_U8(e3_, 3u, pk_);                                               \
    *(unsigned int*)op = pk_;                                                   \
    if (lead) *scp = __half_as_ushort(__float2half_rn(ax_ * (1.0f / 127.0f))); \
    op  += (size_t)I_ * K_;                                                     \
    scp += (size_t)I_ * N_;                                                     \
  } while (0)

#define FMA_BODY(XP)                                                            \
    float2v a01 = {0.f, 0.f}, a23 = {0.f, 0.f};                                 \
    _Pragma("unroll")                                                           \
    for (int p = 0; p < 8; ++p) {                                               \
      pk_fma_lo(a01, (XP)[p], w2[4 * p + 0]);                                   \
      pk_fma_lo(a23, (XP)[p], w2[4 * p + 1]);                                   \
      pk_fma_hi(a01, (XP)[p], w2[4 * p + 2]);                                   \
      pk_fma_hi(a23, (XP)[p], w2[4 * p + 3]);                                   \
    }

  float2v xa[8], xb[8];
#pragma unroll
  for (int p = 0; p < 8; ++p) xa[p] = xlp[p];

  for (int bb = 0; bb < 32; bb += 2) {
#pragma unroll
    for (int p = 0; p < 8; ++p) xb[p] = xlp[(bb + 1) * 8 + p];
    {
      FMA_BODY(xa)
      QUANT_STORE(a01, a23);
    }
    if (bb + 2 < 32) {
#pragma unroll
      for (int p = 0; p < 8; ++p) xa[p] = xlp[(bb + 2) * 8 + p];
    }
    {
      FMA_BODY(xb)
      QUANT_STORE(a01, a23);
    }
  }
#undef FMA_BODY
#undef QUANT_STORE
}

// ---------- routing on u8 u_hat (e = q+128): lane = n; 16 B data + 2 B scale ----------
// u = scale*(e-128); bias folded: dots use (dot_e - 128*sum(v)); s-accum tracks csum.
// MODE 0: c = 1/64 exactly. MODE 1: logit = u.v0. MODE 2: logit = u.(v0+v1).
template <int MODE>
__global__ __launch_bounds__(256, 4) void route_k(const unsigned char* __restrict__ uh,
                                                  const unsigned short* __restrict__ sc,
                                                  const float* __restrict__ sa,
                                                  const float* __restrict__ sb,
                                                  const float* __restrict__ bias,
                                                  float* __restrict__ s_out) {
  const int t    = threadIdx.x;
  const int lane = t & 63;            // = n
  const int wv   = t >> 6;            // 0..3
  const int b    = blockIdx.x >> 4;
  const int iw   = ((blockIdx.x & 15) << 2) + wv;
  const int i0   = iw * 32;

  float vsum[16];
  float voff = 0.f;
  if (MODE >= 1) {
    float bs[16];
#pragma unroll
    for (int q = 0; q < 4; ++q) {
      float4 bb4 = *(const float4*)&bias[lane * 16 + q * 4];
      bs[q*4+0] = bb4.x; bs[q*4+1] = bb4.y; bs[q*4+2] = bb4.z; bs[q*4+3] = bb4.w;
    }
    {
      float va[16], nn = 0.f;
#pragma unroll
      for (int q = 0; q < 4; ++q) {
        float4 tmp = *(const float4*)&sa[(size_t)b * K_ + lane * 16 + q * 4];
        va[q*4+0] = tmp.x + bs[q*4+0]; va[q*4+1] = tmp.y + bs[q*4+1];
        va[q*4+2] = tmp.z + bs[q*4+2]; va[q*4+3] = tmp.w + bs[q*4+3];
      }
#pragma unroll
      for (int d = 0; d < 16; ++d) nn += va[d] * va[d];
      float n2 = nn + 1e-7f;
      float f = sqrtf(n2) / (1.0f + n2);
#pragma unroll
      for (int d = 0; d < 16; ++d) vsum[d] = va[d] * f;
    }
    if (MODE == 2) {
      float vb[16], nn = 0.f;
#pragma unroll
      for (int q = 0; q < 4; ++q) {
        float4 tmp = *(const float4*)&sb[(size_t)b * K_ + lane * 16 + q * 4];
        vb[q*4+0] = tmp.x + bs[q*4+0]; vb[q*4+1] = tmp.y + bs[q*4+1];
        vb[q*4+2] = tmp.z + bs[q*4+2]; vb[q*4+3] = tmp.w + bs[q*4+3];
      }
#pragma unroll
      for (int d = 0; d < 16; ++d) nn += vb[d] * vb[d];
      float n2 = nn + 1e-7f;
      float f = sqrtf(n2) / (1.0f + n2);
#pragma unroll
      for (int d = 0; d < 16; ++d) vsum[d] += vb[d] * f;
    }
    float tv = 0.f;
#pragma unroll
    for (int d = 0; d < 16; ++d) tv += vsum[d];
    voff = 128.0f * tv;
  }

  constexpr int IPW = 32;
  constexpr int PF  = 4;

  const unsigned char*  base = uh + (size_t)b * I_ * K_ + lane * 16;
  const unsigned short* scb  = sc + (size_t)b * I_ * N_ + lane;

  uint4 dbuf[PF];
  unsigned short hbuf[PF];
#pragma unroll
  for (int p = 0; p < PF; ++p) {
    int ip = (i0 + p) & (I_ - 1);
    dbuf[p] = *(const uint4*)(base + (size_t)ip * K_);
    hbuf[p] = scb[(size_t)ip * N_];
  }

  float s_loc[16];
#pragma unroll
  for (int d = 0; d < 16; ++d) s_loc[d] = 0.f;
  float csum = 0.f;

  for (int ii = 0; ii < IPW; ii += PF) {
#pragma unroll
    for (int p = 0; p < PF; ++p) {
      float scale = __half2float(__ushort_as_half(hbuf[p]));
      float u[16];
      {
        unsigned wd;
        wd = dbuf[p].x;   // (float)(byte) -> v_cvt_f32_ubyteN
        u[0]  = (float)(wd & 0xffu);         u[1]  = (float)((wd >> 8) & 0xffu);
        u[2]  = (float)((wd >> 16) & 0xffu); u[3]  = (float)(wd >> 24);
        wd = dbuf[p].y;
        u[4]  = (float)(wd & 0xffu);         u[5]  = (float)((wd >> 8) & 0xffu);
        u[6]  = (float)((wd >> 16) & 0xffu); u[7]  = (float)(wd >> 24);
        wd = dbuf[p].z;
        u[8]  = (float)(wd & 0xffu);         u[9]  = (float)((wd >> 8) & 0xffu);
        u[10] = (float)((wd >> 16) & 0xffu); u[11] = (float)(wd >> 24);
        wd = dbuf[p].w;
        u[12] = (float)(wd & 0xffu);         u[13] = (float)((wd >> 8) & 0xffu);
        u[14] = (float)((wd >> 16) & 0xffu); u[15] = (float)(wd >> 24);
      }

      int ip = (i0 + ii + p + PF) & (I_ - 1);
      dbuf[p] = *(const uint4*)(base + (size_t)ip * K_);
      hbuf[p] = scb[(size_t)ip * N_];

      if (MODE == 0) {
#pragma unroll
        for (int d = 0; d < 16; ++d) s_loc[d] = fmaf(scale, u[d], s_loc[d]);
        csum += scale;
      } else {
        float dot = 0.f;
#pragma unroll
        for (int d = 0; d < 16; ++d) dot = fmaf(u[d], vsum[d], dot);
        float bl = scale * (dot - voff);
        float m = bl;
        m = fmaxf(m, __shfl_xor(m, 1));
        m = fmaxf(m, __shfl_xor(m, 2));
        m = fmaxf(m, __shfl_xor(m, 4));
        m = fmaxf(m, __shfl_xor(m, 8));
        m = fmaxf(m, __shfl_xor(m, 16));
        m = fmaxf(m, __shfl_xor(m, 32));
        float e = __expf(bl - m);
        float ss = e;
        ss += __shfl_xor(ss, 1);
        ss += __shfl_xor(ss, 2);
        ss += __shfl_xor(ss, 4);
        ss += __shfl_xor(ss, 8);
        ss += __shfl_xor(ss, 16);
        ss += __shfl_xor(ss, 32);
        float cs = __fdividef(e, ss) * scale;
#pragma unroll
        for (int d = 0; d < 16; ++d) s_loc[d] = fmaf(cs, u[d], s_loc[d]);
        csum += cs;
      }
    }
  }

  // undo the +128 bias: sum(coeff*scale*(e-128)) = sum(coeff*scale*e) - 128*sum(coeff*scale)
#pragma unroll
  for (int d = 0; d < 16; ++d) s_loc[d] -= 128.0f * csum;
  if (MODE == 0) {
#pragma unroll
    for (int d = 0; d < 16; ++d) s_loc[d] *= (1.0f / 64.0f);
  }

  __shared__ float sred[4][64 * 17];
#pragma unroll
  for (int d = 0; d < 16; ++d) sred[wv][lane * 17 + d] = s_loc[d];
  __syncthreads();
#pragma unroll
  for (int e = 0; e < 4; ++e) {
    int idx = t * 4 + e;
    int n = idx >> 4, d = idx & 15;
    float val = sred[0][n*17+d] + sred[1][n*17+d] + sred[2][n*17+d] + sred[3][n*17+d];
    atomicAdd(&s_out[(size_t)b * K_ + idx], val);
  }
}

// ---------- final squash ----------
__global__ __launch_bounds__(256) void squash_k(const float* __restrict__ s_in,
                                                const float* __restrict__ bias,
                                                float* __restrict__ v_out) {
  const int b = blockIdx.x, t = threadIdx.x, k0 = t * 4;
  float4 s = *(const float4*)&s_in[b * K_ + k0];
  float4 bb = *(const float4*)&bias[k0];
  s.x += bb.x; s.y += bb.y; s.z += bb.z; s.w += bb.w;
  float p = s.x * s.x + s.y * s.y + s.z * s.z + s.w * s.w;
  p += __shfl_xor(p, 1);
  p += __shfl_xor(p, 2);
  float n2 = p + 1e-7f;
  float nrm = sqrtf(n2);
  float f = nrm / (1.0f + n2);
  float4 o = {s.x * f, s.y * f, s.z * f, s.w * f};
  *(float4*)&v_out[b * K_ + k0] = o;
}

extern "C" void kernel_launch(void* const* d_in, const int* in_sizes, int n_in,
                              void* d_out, int out_size, void* d_ws, size_t ws_size,
                              hipStream_t stream) {
  const float* x    = (const float*)d_in[0];
  const float* W    = (const float*)d_in[1];
  const float* bias = (const float*)d_in[2];
  float* out = (float*)d_out;

  char* ws = (char*)d_ws;
  size_t off = 0;
  unsigned char*  uh = (unsigned char*)(ws + off);  off += (size_t)B_ * I_ * K_;      // 134 MB u8
  unsigned short* sc = (unsigned short*)(ws + off); off += (size_t)B_ * I_ * N_ * 2;  // 16.8 MB f16 scales
  float* s0 = (float*)(ws + off); off += (size_t)B_ * K_ * 4;
  float* s1 = (float*)(ws + off); off += (size_t)B_ * K_ * 4;
  float* s2 = (float*)(ws + off); off += (size_t)B_ * K_ * 4;

  if (ws_size < off)
    fprintf(stderr, "ClassCapsule: ws_size=%zu < needed=%zu — expect corruption\n", ws_size, off);

  (void)hipMemsetAsync(s0, 0, (size_t)3 * B_ * K_ * 4, stream);  // s0,s1,s2 contiguous

  project_k<<<dim3(I_ * 2), dim3(256), 0, stream>>>(x, W, uh, sc);

  route_k<0><<<dim3(1024), dim3(256), 0, stream>>>(uh, sc, nullptr, nullptr, bias, s0);
  route_k<1><<<dim3(1024), dim3(256), 0, stream>>>(uh, sc, s0, nullptr, bias, s1);
  route_k<2><<<dim3(1024), dim3(256), 0, stream>>>(uh, sc, s0, s1, bias, s2);
  squash_k<<<dim3(B_), dim3(256), 0, stream>>>(s2, bias, out);
}

// Round 14
// 171.563 us; speedup vs baseline: 1.1570x; 1.1570x over previous
//
#include <hip/hip_runtime.h>
#include <hip/hip_bf16.h>
#include <hip/hip_fp16.h>
#include <cstdio>

#define B_  64
#define I_  2048
#define J_  16
#define N_  64
#define D_  16
#define K_  1024   // N_*D_

using short8 = __attribute__((ext_vector_type(8))) short;
using f32x4  = __attribute__((ext_vector_type(4))) float;

#if __has_builtin(__builtin_amdgcn_cvt_pk_u8_f32)
#define CVTPK_U8(f, sel, old) (unsigned)__builtin_amdgcn_cvt_pk_u8_f32((f), (sel), (old))
#else
__device__ __forceinline__ unsigned cvtpk_u8_sw(float f, unsigned sel, unsigned old) {
  unsigned b = (unsigned)(int)f & 0xffu;
  unsigned sh = sel * 8u;
  return (old & ~(0xffu << sh)) | (b << sh);
}
#define CVTPK_U8(f, sel, old) cvtpk_u8_sw((f), (sel), (old))
#endif

__device__ __forceinline__ short8 pack_bf16x8(float a0, float a1, float a2, float a3,
                                              float a4, float a5, float a6, float a7) {
  __hip_bfloat162 p0 = __float22bfloat162_rn(float2{a0, a1});
  __hip_bfloat162 p1 = __float22bfloat162_rn(float2{a2, a3});
  __hip_bfloat162 p2 = __float22bfloat162_rn(float2{a4, a5});
  __hip_bfloat162 p3 = __float22bfloat162_rn(float2{a6, a7});
  union { unsigned u[4]; short8 s; } cv;
  cv.u[0] = *(unsigned*)&p0; cv.u[1] = *(unsigned*)&p1;
  cv.u[2] = *(unsigned*)&p2; cv.u[3] = *(unsigned*)&p3;
  return cv.s;
}

// ---------- projection via MFMA: one block per i; D[k][b] = W^T x^T ----------
// mfma_f32_16x16x32_bf16 (layouts HW-validated by round-8 s0_gemm):
//   A frag: lane l = A[row=l&15][kappa=(l>>4)*8+e]  -> W[j=kappa][k=row] (0 for kappa>=16)
//   B frag: lane l = B[kappa=(l>>4)*8+e][col=l&15]  -> x[b=col][j=kappa] (0 for kappa>=16)
//   D frag: col=l&15 (b), row=(l>>4)*4+r (k in tile)  [m89-verified]
// 4 waves = 4 b-tiles of 16; loop 4 phases x 16 k-tiles. Quant: lane's 4 vals =
// 4 consecutive k of ONE b -> in-lane max + shfl_xor(16,32) + cvt_pk_u8 dword.
// Out staged in XOR-swizzled LDS, flushed coalesced per phase.
__global__ __launch_bounds__(256) void project_k(const float* __restrict__ x,
                                                 const float* __restrict__ W,
                                                 unsigned char* __restrict__ uh,
                                                 unsigned short* __restrict__ sc) {
  const int i  = blockIdx.x;
  const int t  = threadIdx.x;
  const int l  = t & 63;
  const int wv = t >> 6;

  __shared__ unsigned short lds_w[256 * 20];   // 10 KB: W chunk [k_local][j], pad 20
  __shared__ float          lds_x[64 * 20];    // 5 KB: x rows [b][j], pad 20
  __shared__ unsigned int   out_lds[64 * 64];  // 16 KB: [b][64 dwords], swizzled
  __shared__ unsigned short sc_lds[64 * 20];   // 2.5 KB: [b][16 nt], pad 20

  // stage x[.][i][.] for all 64 b
  {
    int b = t >> 2, q = t & 3;
    float4 v = ((const float4*)(x + ((size_t)b * I_ + i) * J_))[q];
    *(float4*)&lds_x[b * 20 + q * 4] = v;
  }
  __syncthreads();

  // x B-frag (constant all kernel): col = b = wv*16+(l&15), kappa=j=(l>>4)*8+e
  short8 xfrag = {0, 0, 0, 0, 0, 0, 0, 0};
  if (l < 32) {
    int b = wv * 16 + (l & 15);
    const float* xp = &lds_x[b * 20 + (l >> 4) * 8];
    float4 f0 = *(const float4*)xp;
    float4 f1 = *(const float4*)(xp + 4);
    xfrag = pack_bf16x8(f0.x, f0.y, f0.z, f0.w, f1.x, f1.y, f1.z, f1.w);
  }

  for (int ph = 0; ph < 4; ++ph) {
    // stage W[j][k = ph*256 + t] -> lds_w[t][j] bf16 (16 coalesced dword loads)
    {
      const float* wp = W + (size_t)i * (J_ * K_) + ph * 256 + t;
      float wj[J_];
#pragma unroll
      for (int j = 0; j < J_; ++j) wj[j] = wp[(size_t)j * K_];
#pragma unroll
      for (int q = 0; q < 4; ++q) {
        __hip_bfloat162 pA = __float22bfloat162_rn(float2{wj[4*q+0], wj[4*q+1]});
        __hip_bfloat162 pB = __float22bfloat162_rn(float2{wj[4*q+2], wj[4*q+3]});
        uint2 u; u.x = *(unsigned*)&pA; u.y = *(unsigned*)&pB;
        *(uint2*)&lds_w[t * 20 + q * 4] = u;       // byte 40t+8q, 8-aligned
      }
    }
    __syncthreads();

#pragma unroll
    for (int ntl = 0; ntl < 16; ++ntl) {
      short8 afrag = {0, 0, 0, 0, 0, 0, 0, 0};
      if (l < 32) {
        int krow = ntl * 16 + (l & 15);
        const unsigned short* ap = &lds_w[krow * 20 + (l >> 4) * 8];
        union { uint2 u2[2]; short8 s; } cv;
        cv.u2[0] = *(const uint2*)ap;              // byte 40k+16jh, 8-aligned
        cv.u2[1] = *(const uint2*)(ap + 4);
        afrag = cv.s;
      }
      f32x4 acc = {0.f, 0.f, 0.f, 0.f};
      acc = __builtin_amdgcn_mfma_f32_16x16x32_bf16(afrag, xfrag, acc, 0, 0, 0);

      const int b = wv * 16 + (l & 15);            // D col
      float ax = fmaxf(fmaxf(fabsf(acc[0]), fabsf(acc[1])),
                       fmaxf(fabsf(acc[2]), fabsf(acc[3])));
      ax = fmaxf(ax, __shfl_xor(ax, 16));
      ax = fmaxf(ax, __shfl_xor(ax, 32));
      float inv = __fdividef(127.0f, fmaxf(ax, 1e-30f));
      float e0 = rintf(fmaf(acc[0], inv, 128.f));
      float e1 = rintf(fmaf(acc[1], inv, 128.f));
      float e2 = rintf(fmaf(acc[2], inv, 128.f));
      float e3 = rintf(fmaf(acc[3], inv, 128.f));
      unsigned pk = CVTPK_U8(e0, 0u, 0u);
      pk = CVTPK_U8(e1, 1u, pk);
      pk = CVTPK_U8(e2, 2u, pk);
      pk = CVTPK_U8(e3, 3u, pk);
      int kd = ntl * 4 + (l >> 4);                 // dword index in row (per phase)
      out_lds[b * 64 + (kd ^ ((b & 7) << 2))] = pk;
      if (l < 16)                                   // one lane per b in this wave
        sc_lds[b * 20 + ntl] = __half_as_ushort(__float2half_rn(ax * (1.0f / 127.0f)));
    }
    __syncthreads();

    // flush u8 data (coalesced: 16 lanes x 16 B = 256 B per b-row)
    {
      int c = t & 15;
#pragma unroll
      for (int it = 0; it < 4; ++it) {
        int b = (t >> 4) + it * 16;
        uint4 v = *(const uint4*)&out_lds[b * 64 + ((c * 4) ^ ((b & 7) << 2))];
        *(uint4*)(uh + (size_t)b * I_ * K_ + (size_t)i * K_ + ph * 256 + c * 16) = v;
      }
      // flush scales (n = ph*16 + ntl)
      int b2 = t >> 2, n4 = (t & 3) * 4;
      uint2 sv = *(const uint2*)&sc_lds[b2 * 20 + n4];
      *(uint2*)(sc + (size_t)b2 * I_ * N_ + (size_t)i * N_ + ph * 16 + n4) = sv;
    }
    __syncthreads();
  }
}

// ---------- routing on u8 u_hat (e = q+128): lane = n; 16 B data + 2 B scale ----------
// (unchanged from round 13 — proven at ~28 us each)
template <int MODE>
__global__ __launch_bounds__(256, 4) void route_k(const unsigned char* __restrict__ uh,
                                                  const unsigned short* __restrict__ sc,
                                                  const float* __restrict__ sa,
                                                  const float* __restrict__ sb,
                                                  const float* __restrict__ bias,
                                                  float* __restrict__ s_out) {
  const int t    = threadIdx.x;
  const int lane = t & 63;            // = n
  const int wv   = t >> 6;            // 0..3
  const int b    = blockIdx.x >> 4;
  const int iw   = ((blockIdx.x & 15) << 2) + wv;
  const int i0   = iw * 32;

  float vsum[16];
  float voff = 0.f;
  if (MODE >= 1) {
    float bs[16];
#pragma unroll
    for (int q = 0; q < 4; ++q) {
      float4 bb4 = *(const float4*)&bias[lane * 16 + q * 4];
      bs[q*4+0] = bb4.x; bs[q*4+1] = bb4.y; bs[q*4+2] = bb4.z; bs[q*4+3] = bb4.w;
    }
    {
      float va[16], nn = 0.f;
#pragma unroll
      for (int q = 0; q < 4; ++q) {
        float4 tmp = *(const float4*)&sa[(size_t)b * K_ + lane * 16 + q * 4];
        va[q*4+0] = tmp.x + bs[q*4+0]; va[q*4+1] = tmp.y + bs[q*4+1];
        va[q*4+2] = tmp.z + bs[q*4+2]; va[q*4+3] = tmp.w + bs[q*4+3];
      }
#pragma unroll
      for (int d = 0; d < 16; ++d) nn += va[d] * va[d];
      float n2 = nn + 1e-7f;
      float f = sqrtf(n2) / (1.0f + n2);
#pragma unroll
      for (int d = 0; d < 16; ++d) vsum[d] = va[d] * f;
    }
    if (MODE == 2) {
      float vb[16], nn = 0.f;
#pragma unroll
      for (int q = 0; q < 4; ++q) {
        float4 tmp = *(const float4*)&sb[(size_t)b * K_ + lane * 16 + q * 4];
        vb[q*4+0] = tmp.x + bs[q*4+0]; vb[q*4+1] = tmp.y + bs[q*4+1];
        vb[q*4+2] = tmp.z + bs[q*4+2]; vb[q*4+3] = tmp.w + bs[q*4+3];
      }
#pragma unroll
      for (int d = 0; d < 16; ++d) nn += vb[d] * vb[d];
      float n2 = nn + 1e-7f;
      float f = sqrtf(n2) / (1.0f + n2);
#pragma unroll
      for (int d = 0; d < 16; ++d) vsum[d] += vb[d] * f;
    }
    float tv = 0.f;
#pragma unroll
    for (int d = 0; d < 16; ++d) tv += vsum[d];
    voff = 128.0f * tv;
  }

  constexpr int IPW = 32;
  constexpr int PF  = 4;

  const unsigned char*  base = uh + (size_t)b * I_ * K_ + lane * 16;
  const unsigned short* scb  = sc + (size_t)b * I_ * N_ + lane;

  uint4 dbuf[PF];
  unsigned short hbuf[PF];
#pragma unroll
  for (int p = 0; p < PF; ++p) {
    int ip = (i0 + p) & (I_ - 1);
    dbuf[p] = *(const uint4*)(base + (size_t)ip * K_);
    hbuf[p] = scb[(size_t)ip * N_];
  }

  float s_loc[16];
#pragma unroll
  for (int d = 0; d < 16; ++d) s_loc[d] = 0.f;
  float csum = 0.f;

  for (int ii = 0; ii < IPW; ii += PF) {
#pragma unroll
    for (int p = 0; p < PF; ++p) {
      float scale = __half2float(__ushort_as_half(hbuf[p]));
      float u[16];
      {
        unsigned wd;
        wd = dbuf[p].x;
        u[0]  = (float)(wd & 0xffu);         u[1]  = (float)((wd >> 8) & 0xffu);
        u[2]  = (float)((wd >> 16) & 0xffu); u[3]  = (float)(wd >> 24);
        wd = dbuf[p].y;
        u[4]  = (float)(wd & 0xffu);         u[5]  = (float)((wd >> 8) & 0xffu);
        u[6]  = (float)((wd >> 16) & 0xffu); u[7]  = (float)(wd >> 24);
        wd = dbuf[p].z;
        u[8]  = (float)(wd & 0xffu);         u[9]  = (float)((wd >> 8) & 0xffu);
        u[10] = (float)((wd >> 16) & 0xffu); u[11] = (float)(wd >> 24);
        wd = dbuf[p].w;
        u[12] = (float)(wd & 0xffu);         u[13] = (float)((wd >> 8) & 0xffu);
        u[14] = (float)((wd >> 16) & 0xffu); u[15] = (float)(wd >> 24);
      }

      int ip = (i0 + ii + p + PF) & (I_ - 1);
      dbuf[p] = *(const uint4*)(base + (size_t)ip * K_);
      hbuf[p] = scb[(size_t)ip * N_];

      if (MODE == 0) {
#pragma unroll
        for (int d = 0; d < 16; ++d) s_loc[d] = fmaf(scale, u[d], s_loc[d]);
        csum += scale;
      } else {
        float dot = 0.f;
#pragma unroll
        for (int d = 0; d < 16; ++d) dot = fmaf(u[d], vsum[d], dot);
        float bl = scale * (dot - voff);
        float m = bl;
        m = fmaxf(m, __shfl_xor(m, 1));
        m = fmaxf(m, __shfl_xor(m, 2));
        m = fmaxf(m, __shfl_xor(m, 4));
        m = fmaxf(m, __shfl_xor(m, 8));
        m = fmaxf(m, __shfl_xor(m, 16));
        m = fmaxf(m, __shfl_xor(m, 32));
        float e = __expf(bl - m);
        float ss = e;
        ss += __shfl_xor(ss, 1);
        ss += __shfl_xor(ss, 2);
        ss += __shfl_xor(ss, 4);
        ss += __shfl_xor(ss, 8);
        ss += __shfl_xor(ss, 16);
        ss += __shfl_xor(ss, 32);
        float cs = __fdividef(e, ss) * scale;
#pragma unroll
        for (int d = 0; d < 16; ++d) s_loc[d] = fmaf(cs, u[d], s_loc[d]);
        csum += cs;
      }
    }
  }

#pragma unroll
  for (int d = 0; d < 16; ++d) s_loc[d] -= 128.0f * csum;
  if (MODE == 0) {
#pragma unroll
    for (int d = 0; d < 16; ++d) s_loc[d] *= (1.0f / 64.0f);
  }

  __shared__ float sred[4][64 * 17];
#pragma unroll
  for (int d = 0; d < 16; ++d) sred[wv][lane * 17 + d] = s_loc[d];
  __syncthreads();
#pragma unroll
  for (int e = 0; e < 4; ++e) {
    int idx = t * 4 + e;
    int n = idx >> 4, d = idx & 15;
    float val = sred[0][n*17+d] + sred[1][n*17+d] + sred[2][n*17+d] + sred[3][n*17+d];
    atomicAdd(&s_out[(size_t)b * K_ + idx], val);
  }
}

// ---------- final squash ----------
__global__ __launch_bounds__(256) void squash_k(const float* __restrict__ s_in,
                                                const float* __restrict__ bias,
                                                float* __restrict__ v_out) {
  const int b = blockIdx.x, t = threadIdx.x, k0 = t * 4;
  float4 s = *(const float4*)&s_in[b * K_ + k0];
  float4 bb = *(const float4*)&bias[k0];
  s.x += bb.x; s.y += bb.y; s.z += bb.z; s.w += bb.w;
  float p = s.x * s.x + s.y * s.y + s.z * s.z + s.w * s.w;
  p += __shfl_xor(p, 1);
  p += __shfl_xor(p, 2);
  float n2 = p + 1e-7f;
  float nrm = sqrtf(n2);
  float f = nrm / (1.0f + n2);
  float4 o = {s.x * f, s.y * f, s.z * f, s.w * f};
  *(float4*)&v_out[b * K_ + k0] = o;
}

extern "C" void kernel_launch(void* const* d_in, const int* in_sizes, int n_in,
                              void* d_out, int out_size, void* d_ws, size_t ws_size,
                              hipStream_t stream) {
  const float* x    = (const float*)d_in[0];
  const float* W    = (const float*)d_in[1];
  const float* bias = (const float*)d_in[2];
  float* out = (float*)d_out;

  char* ws = (char*)d_ws;
  size_t off = 0;
  unsigned char*  uh = (unsigned char*)(ws + off);  off += (size_t)B_ * I_ * K_;      // 134 MB u8
  unsigned short* sc = (unsigned short*)(ws + off); off += (size_t)B_ * I_ * N_ * 2;  // 16.8 MB f16 scales
  float* s0 = (float*)(ws + off); off += (size_t)B_ * K_ * 4;
  float* s1 = (float*)(ws + off); off += (size_t)B_ * K_ * 4;
  float* s2 = (float*)(ws + off); off += (size_t)B_ * K_ * 4;

  if (ws_size < off)
    fprintf(stderr, "ClassCapsule: ws_size=%zu < needed=%zu — expect corruption\n", ws_size, off);

  (void)hipMemsetAsync(s0, 0, (size_t)3 * B_ * K_ * 4, stream);  // s0,s1,s2 contiguous

  project_k<<<dim3(I_), dim3(256), 0, stream>>>(x, W, uh, sc);

  route_k<0><<<dim3(1024), dim3(256), 0, stream>>>(uh, sc, nullptr, nullptr, bias, s0);
  route_k<1><<<dim3(1024), dim3(256), 0, stream>>>(uh, sc, s0, nullptr, bias, s1);
  route_k<2><<<dim3(1024), dim3(256), 0, stream>>>(uh, sc, s0, s1, bias, s2);
  squash_k<<<dim3(B_), dim3(256), 0, stream>>>(s2, bias, out);
}

// Round 15
// 166.810 us; speedup vs baseline: 1.1900x; 1.0285x over previous
//
#include <hip/hip_runtime.h>
#include <hip/hip_bf16.h>
#include <hip/hip_fp16.h>
#include <cstdio>

#define B_  64
#define I_  2048
#define J_  16
#define N_  64
#define D_  16
#define K_  1024   // N_*D_

using short8 = __attribute__((ext_vector_type(8))) short;
using f32x16 = __attribute__((ext_vector_type(16))) float;

#if __has_builtin(__builtin_amdgcn_cvt_pk_u8_f32)
#define CVTPK_U8(f, sel, old) (unsigned)__builtin_amdgcn_cvt_pk_u8_f32((f), (sel), (old))
#else
__device__ __forceinline__ unsigned cvtpk_u8_sw(float f, unsigned sel, unsigned old) {
  unsigned b = (unsigned)(int)f & 0xffu;
  unsigned sh = sel * 8u;
  return (old & ~(0xffu << sh)) | (b << sh);
}
#define CVTPK_U8(f, sel, old) cvtpk_u8_sw((f), (sel), (old))
#endif

__device__ __forceinline__ short8 pack_bf16x8(float a0, float a1, float a2, float a3,
                                              float a4, float a5, float a6, float a7) {
  __hip_bfloat162 p0 = __float22bfloat162_rn(float2{a0, a1});
  __hip_bfloat162 p1 = __float22bfloat162_rn(float2{a2, a3});
  __hip_bfloat162 p2 = __float22bfloat162_rn(float2{a4, a5});
  __hip_bfloat162 p3 = __float22bfloat162_rn(float2{a6, a7});
  union { unsigned u[4]; short8 s; } cv;
  cv.u[0] = *(unsigned*)&p0; cv.u[1] = *(unsigned*)&p1;
  cv.u[2] = *(unsigned*)&p2; cv.u[3] = *(unsigned*)&p3;
  return cv.s;
}

// ---------- projection via MFMA 32x32x16 (K = j = 16, no padding) ----------
// One block per i. D[k_tile=32][b_tile=32] = W^T x^T.
//   A frag: lane l = A[row=l&31][kappa=(l>>5)*8+e] -> W[j=kappa][k=kt*32+row]
//   B frag: lane l = B[kappa=(l>>5)*8+e][col=l&31] -> x[b=btile*32+col][j=kappa]
//   D frag: col=l&31 (b), row=(reg&3)+8*(reg>>2)+4*(l>>5)  [m74/m101-verified]
//     -> reg block cs*8+r covers capsule cs: d=(r&3)+8*(r>>2)+4h (h=l>>5)
// 4 waves: (wv&1)=b-tile, (wv>>1)*4+kk = k-tile. 4 phases x 8 k-tiles.
// Quant per capsule: 7 in-lane max + ONE shfl_xor(32); pack 2 dwords; LDS-stage
// swizzled; coalesced flush. Scales f16 per (b,i,n).
__global__ __launch_bounds__(256) void project_k(const float* __restrict__ x,
                                                 const float* __restrict__ W,
                                                 unsigned char* __restrict__ uh,
                                                 unsigned short* __restrict__ sc) {
  const int i  = blockIdx.x;
  const int t  = threadIdx.x;
  const int l  = t & 63;
  const int wv = t >> 6;
  const int h  = l >> 5;        // kappa half / d-offset selector
  const int lr = l & 31;        // row (A) / col (B,D)

  __shared__ unsigned short lds_w[256 * 20];   // 10 KB  [k_local][j] pad 20
  __shared__ float          lds_x[64 * 20];    // 5 KB   [b][j] pad 20
  __shared__ unsigned int   out_lds[64 * 64];  // 16 KB  [b][64 dwords] swizzled
  __shared__ unsigned short sc_lds[64 * 20];   // 2.5 KB [b][16] pad 20

  // stage x rows for all 64 b
  {
    int b = t >> 2, q = t & 3;
    float4 v = ((const float4*)(x + ((size_t)b * I_ + i) * J_))[q];
    *(float4*)&lds_x[b * 20 + q * 4] = v;
  }
  __syncthreads();

  // B-frag (constant over phases): b = (wv&1)*32 + lr, j = h*8+e
  short8 xfrag;
  {
    int b = (wv & 1) * 32 + lr;
    const float* xp = &lds_x[b * 20 + h * 8];
    float4 f0 = *(const float4*)xp;
    float4 f1 = *(const float4*)(xp + 4);
    xfrag = pack_bf16x8(f0.x, f0.y, f0.z, f0.w, f1.x, f1.y, f1.z, f1.w);
  }

  const int b  = (wv & 1) * 32 + lr;       // D column owned by this lane
  const unsigned sw = (unsigned)((b & 7) << 2);
  const int kt_base = (wv >> 1) * 4;

  for (int ph = 0; ph < 4; ++ph) {
    // stage W[j][ph*256 + k] -> lds_w[k_local][j] bf16 (4x float4 + 4x4 transpose)
    {
      const float* wp = W + (size_t)i * (J_ * K_) + ph * 256;
      const int j0 = (t & 3) * 4;
      const int kg = t >> 2;               // 0..63 -> k_local = kg*4..kg*4+3
      float4 r0 = *(const float4*)(wp + (size_t)(j0 + 0) * K_ + kg * 4);
      float4 r1 = *(const float4*)(wp + (size_t)(j0 + 1) * K_ + kg * 4);
      float4 r2 = *(const float4*)(wp + (size_t)(j0 + 2) * K_ + kg * 4);
      float4 r3 = *(const float4*)(wp + (size_t)(j0 + 3) * K_ + kg * 4);
      const float* p0 = (const float*)&r0;
      const float* p1 = (const float*)&r1;
      const float* p2 = (const float*)&r2;
      const float* p3 = (const float*)&r3;
#pragma unroll
      for (int kk = 0; kk < 4; ++kk) {
        __hip_bfloat162 pA = __float22bfloat162_rn(float2{p0[kk], p1[kk]});
        __hip_bfloat162 pB = __float22bfloat162_rn(float2{p2[kk], p3[kk]});
        uint2 u; u.x = *(unsigned*)&pA; u.y = *(unsigned*)&pB;
        *(uint2*)&lds_w[(kg * 4 + kk) * 20 + j0] = u;
      }
    }
    __syncthreads();

#pragma unroll
    for (int kk = 0; kk < 4; ++kk) {
      const int kt = kt_base + kk;         // 0..7 (k-tile of 32 within phase)
      // A-frag: row = kt*32+lr, j = h*8+e
      const unsigned short* ap = &lds_w[(kt * 32 + lr) * 20 + h * 8];
      union { uint2 u2[2]; short8 s; } cv;
      cv.u2[0] = *(const uint2*)ap;
      cv.u2[1] = *(const uint2*)(ap + 4);
      f32x16 acc = {0.f, 0.f, 0.f, 0.f, 0.f, 0.f, 0.f, 0.f,
                    0.f, 0.f, 0.f, 0.f, 0.f, 0.f, 0.f, 0.f};
      acc = __builtin_amdgcn_mfma_f32_32x32x16_bf16(cv.s, xfrag, acc, 0, 0, 0);

#define QCAP(C8, CS) do {                                                       \
      float ax = fabsf(acc[(C8) + 0]);                                          \
      ax = fmaxf(ax, fabsf(acc[(C8) + 1]));                                     \
      ax = fmaxf(ax, fabsf(acc[(C8) + 2]));                                     \
      ax = fmaxf(ax, fabsf(acc[(C8) + 3]));                                     \
      ax = fmaxf(ax, fabsf(acc[(C8) + 4]));                                     \
      ax = fmaxf(ax, fabsf(acc[(C8) + 5]));                                     \
      ax = fmaxf(ax, fabsf(acc[(C8) + 6]));                                     \
      ax = fmaxf(ax, fabsf(acc[(C8) + 7]));                                     \
      ax = fmaxf(ax, __shfl_xor(ax, 32));                                       \
      float inv = __fdividef(127.0f, fmaxf(ax, 1e-30f));                        \
      unsigned pk0 = CVTPK_U8(rintf(fmaf(acc[(C8) + 0], inv, 128.f)), 0u, 0u);  \
      pk0 = CVTPK_U8(rintf(fmaf(acc[(C8) + 1], inv, 128.f)), 1u, pk0);          \
      pk0 = CVTPK_U8(rintf(fmaf(acc[(C8) + 2], inv, 128.f)), 2u, pk0);          \
      pk0 = CVTPK_U8(rintf(fmaf(acc[(C8) + 3], inv, 128.f)), 3u, pk0);          \
      unsigned pk1 = CVTPK_U8(rintf(fmaf(acc[(C8) + 4], inv, 128.f)), 0u, 0u);  \
      pk1 = CVTPK_U8(rintf(fmaf(acc[(C8) + 5], inv, 128.f)), 1u, pk1);          \
      pk1 = CVTPK_U8(rintf(fmaf(acc[(C8) + 6], inv, 128.f)), 2u, pk1);          \
      pk1 = CVTPK_U8(rintf(fmaf(acc[(C8) + 7], inv, 128.f)), 3u, pk1);          \
      const int ibase = kt * 8 + (CS) * 4;                                      \
      out_lds[b * 64 + ((unsigned)(ibase + h)     ^ sw)] = pk0;                 \
      out_lds[b * 64 + ((unsigned)(ibase + 2 + h) ^ sw)] = pk1;                 \
      if (h == 0)                                                               \
        sc_lds[b * 20 + kt * 2 + (CS)] =                                        \
            __half_as_ushort(__float2half_rn(ax * (1.0f / 127.0f)));            \
    } while (0)

      QCAP(0, 0);   // capsule cs=0: regs 0-7,  d=(r&3)+8*(r>>2)+4h
      QCAP(8, 1);   // capsule cs=1: regs 8-15
#undef QCAP
    }
    __syncthreads();

    // flush u8 data (coalesced 16B/lane) + scales
    {
      const int c = t & 15;
#pragma unroll
      for (int it = 0; it < 4; ++it) {
        int bf = (t >> 4) + it * 16;
        uint4 v = *(const uint4*)&out_lds[bf * 64 + (((unsigned)(c * 4)) ^ ((unsigned)((bf & 7) << 2)))];
        *(uint4*)(uh + (size_t)bf * I_ * K_ + (size_t)i * K_ + ph * 256 + c * 16) = v;
      }
      int b2 = t >> 2, n4 = (t & 3) * 4;
      uint2 sv = *(const uint2*)&sc_lds[b2 * 20 + n4];
      *(uint2*)(sc + (size_t)b2 * I_ * N_ + (size_t)i * N_ + ph * 16 + n4) = sv;
    }
    __syncthreads();
  }
}

// ---------- routing on u8 u_hat (e = q+128): lane = n; 16 B data + 2 B scale ----------
// (unchanged — proven ~18 us each, L3-resident)
template <int MODE>
__global__ __launch_bounds__(256, 4) void route_k(const unsigned char* __restrict__ uh,
                                                  const unsigned short* __restrict__ sc,
                                                  const float* __restrict__ sa,
                                                  const float* __restrict__ sb,
                                                  const float* __restrict__ bias,
                                                  float* __restrict__ s_out) {
  const int t    = threadIdx.x;
  const int lane = t & 63;            // = n
  const int wv   = t >> 6;            // 0..3
  const int b    = blockIdx.x >> 4;
  const int iw   = ((blockIdx.x & 15) << 2) + wv;
  const int i0   = iw * 32;

  float vsum[16];
  float voff = 0.f;
  if (MODE >= 1) {
    float bs[16];
#pragma unroll
    for (int q = 0; q < 4; ++q) {
      float4 bb4 = *(const float4*)&bias[lane * 16 + q * 4];
      bs[q*4+0] = bb4.x; bs[q*4+1] = bb4.y; bs[q*4+2] = bb4.z; bs[q*4+3] = bb4.w;
    }
    {
      float va[16], nn = 0.f;
#pragma unroll
      for (int q = 0; q < 4; ++q) {
        float4 tmp = *(const float4*)&sa[(size_t)b * K_ + lane * 16 + q * 4];
        va[q*4+0] = tmp.x + bs[q*4+0]; va[q*4+1] = tmp.y + bs[q*4+1];
        va[q*4+2] = tmp.z + bs[q*4+2]; va[q*4+3] = tmp.w + bs[q*4+3];
      }
#pragma unroll
      for (int d = 0; d < 16; ++d) nn += va[d] * va[d];
      float n2 = nn + 1e-7f;
      float f = sqrtf(n2) / (1.0f + n2);
#pragma unroll
      for (int d = 0; d < 16; ++d) vsum[d] = va[d] * f;
    }
    if (MODE == 2) {
      float vb[16], nn = 0.f;
#pragma unroll
      for (int q = 0; q < 4; ++q) {
        float4 tmp = *(const float4*)&sb[(size_t)b * K_ + lane * 16 + q * 4];
        vb[q*4+0] = tmp.x + bs[q*4+0]; vb[q*4+1] = tmp.y + bs[q*4+1];
        vb[q*4+2] = tmp.z + bs[q*4+2]; vb[q*4+3] = tmp.w + bs[q*4+3];
      }
#pragma unroll
      for (int d = 0; d < 16; ++d) nn += vb[d] * vb[d];
      float n2 = nn + 1e-7f;
      float f = sqrtf(n2) / (1.0f + n2);
#pragma unroll
      for (int d = 0; d < 16; ++d) vsum[d] += vb[d] * f;
    }
    float tv = 0.f;
#pragma unroll
    for (int d = 0; d < 16; ++d) tv += vsum[d];
    voff = 128.0f * tv;
  }

  constexpr int IPW = 32;
  constexpr int PF  = 4;

  const unsigned char*  base = uh + (size_t)b * I_ * K_ + lane * 16;
  const unsigned short* scb  = sc + (size_t)b * I_ * N_ + lane;

  uint4 dbuf[PF];
  unsigned short hbuf[PF];
#pragma unroll
  for (int p = 0; p < PF; ++p) {
    int ip = (i0 + p) & (I_ - 1);
    dbuf[p] = *(const uint4*)(base + (size_t)ip * K_);
    hbuf[p] = scb[(size_t)ip * N_];
  }

  float s_loc[16];
#pragma unroll
  for (int d = 0; d < 16; ++d) s_loc[d] = 0.f;
  float csum = 0.f;

  for (int ii = 0; ii < IPW; ii += PF) {
#pragma unroll
    for (int p = 0; p < PF; ++p) {
      float scale = __half2float(__ushort_as_half(hbuf[p]));
      float u[16];
      {
        unsigned wd;
        wd = dbuf[p].x;
        u[0]  = (float)(wd & 0xffu);         u[1]  = (float)((wd >> 8) & 0xffu);
        u[2]  = (float)((wd >> 16) & 0xffu); u[3]  = (float)(wd >> 24);
        wd = dbuf[p].y;
        u[4]  = (float)(wd & 0xffu);         u[5]  = (float)((wd >> 8) & 0xffu);
        u[6]  = (float)((wd >> 16) & 0xffu); u[7]  = (float)(wd >> 24);
        wd = dbuf[p].z;
        u[8]  = (float)(wd & 0xffu);         u[9]  = (float)((wd >> 8) & 0xffu);
        u[10] = (float)((wd >> 16) & 0xffu); u[11] = (float)(wd >> 24);
        wd = dbuf[p].w;
        u[12] = (float)(wd & 0xffu);         u[13] = (float)((wd >> 8) & 0xffu);
        u[14] = (float)((wd >> 16) & 0xffu); u[15] = (float)(wd >> 24);
      }

      int ip = (i0 + ii + p + PF) & (I_ - 1);
      dbuf[p] = *(const uint4*)(base + (size_t)ip * K_);
      hbuf[p] = scb[(size_t)ip * N_];

      if (MODE == 0) {
#pragma unroll
        for (int d = 0; d < 16; ++d) s_loc[d] = fmaf(scale, u[d], s_loc[d]);
        csum += scale;
      } else {
        float dot = 0.f;
#pragma unroll
        for (int d = 0; d < 16; ++d) dot = fmaf(u[d], vsum[d], dot);
        float bl = scale * (dot - voff);
        float m = bl;
        m = fmaxf(m, __shfl_xor(m, 1));
        m = fmaxf(m, __shfl_xor(m, 2));
        m = fmaxf(m, __shfl_xor(m, 4));
        m = fmaxf(m, __shfl_xor(m, 8));
        m = fmaxf(m, __shfl_xor(m, 16));
        m = fmaxf(m, __shfl_xor(m, 32));
        float e = __expf(bl - m);
        float ss = e;
        ss += __shfl_xor(ss, 1);
        ss += __shfl_xor(ss, 2);
        ss += __shfl_xor(ss, 4);
        ss += __shfl_xor(ss, 8);
        ss += __shfl_xor(ss, 16);
        ss += __shfl_xor(ss, 32);
        float cs = __fdividef(e, ss) * scale;
#pragma unroll
        for (int d = 0; d < 16; ++d) s_loc[d] = fmaf(cs, u[d], s_loc[d]);
        csum += cs;
      }
    }
  }

#pragma unroll
  for (int d = 0; d < 16; ++d) s_loc[d] -= 128.0f * csum;
  if (MODE == 0) {
#pragma unroll
    for (int d = 0; d < 16; ++d) s_loc[d] *= (1.0f / 64.0f);
  }

  __shared__ float sred[4][64 * 17];
#pragma unroll
  for (int d = 0; d < 16; ++d) sred[wv][lane * 17 + d] = s_loc[d];
  __syncthreads();
#pragma unroll
  for (int e = 0; e < 4; ++e) {
    int idx = t * 4 + e;
    int n = idx >> 4, d = idx & 15;
    float val = sred[0][n*17+d] + sred[1][n*17+d] + sred[2][n*17+d] + sred[3][n*17+d];
    atomicAdd(&s_out[(size_t)b * K_ + idx], val);
  }
}

// ---------- final squash ----------
__global__ __launch_bounds__(256) void squash_k(const float* __restrict__ s_in,
                                                const float* __restrict__ bias,
                                                float* __restrict__ v_out) {
  const int b = blockIdx.x, t = threadIdx.x, k0 = t * 4;
  float4 s = *(const float4*)&s_in[b * K_ + k0];
  float4 bb = *(const float4*)&bias[k0];
  s.x += bb.x; s.y += bb.y; s.z += bb.z; s.w += bb.w;
  float p = s.x * s.x + s.y * s.y + s.z * s.z + s.w * s.w;
  p += __shfl_xor(p, 1);
  p += __shfl_xor(p, 2);
  float n2 = p + 1e-7f;
  float nrm = sqrtf(n2);
  float f = nrm / (1.0f + n2);
  float4 o = {s.x * f, s.y * f, s.z * f, s.w * f};
  *(float4*)&v_out[b * K_ + k0] = o;
}

extern "C" void kernel_launch(void* const* d_in, const int* in_sizes, int n_in,
                              void* d_out, int out_size, void* d_ws, size_t ws_size,
                              hipStream_t stream) {
  const float* x    = (const float*)d_in[0];
  const float* W    = (const float*)d_in[1];
  const float* bias = (const float*)d_in[2];
  float* out = (float*)d_out;

  char* ws = (char*)d_ws;
  size_t off = 0;
  unsigned char*  uh = (unsigned char*)(ws + off);  off += (size_t)B_ * I_ * K_;      // 134 MB u8
  unsigned short* sc = (unsigned short*)(ws + off); off += (size_t)B_ * I_ * N_ * 2;  // 16.8 MB f16 scales
  float* s0 = (float*)(ws + off); off += (size_t)B_ * K_ * 4;
  float* s1 = (float*)(ws + off); off += (size_t)B_ * K_ * 4;
  float* s2 = (float*)(ws + off); off += (size_t)B_ * K_ * 4;

  if (ws_size < off)
    fprintf(stderr, "ClassCapsule: ws_size=%zu < needed=%zu — expect corruption\n", ws_size, off);

  (void)hipMemsetAsync(s0, 0, (size_t)3 * B_ * K_ * 4, stream);  // s0,s1,s2 contiguous

  project_k<<<dim3(I_), dim3(256), 0, stream>>>(x, W, uh, sc);

  route_k<0><<<dim3(1024), dim3(256), 0, stream>>>(uh, sc, nullptr, nullptr, bias, s0);
  route_k<1><<<dim3(1024), dim3(256), 0, stream>>>(uh, sc, s0, nullptr, bias, s1);
  route_k<2><<<dim3(1024), dim3(256), 0, stream>>>(uh, sc, s0, s1, bias, s2);
  squash_k<<<dim3(B_), dim3(256), 0, stream>>>(s2, bias, out);
}

// Round 16
// 162.398 us; speedup vs baseline: 1.2223x; 1.0272x over previous
//
#include <hip/hip_runtime.h>
#include <hip/hip_bf16.h>
#include <hip/hip_fp16.h>
#include <cstdio>

#define B_  64
#define I_  2048
#define J_  16
#define N_  64
#define D_  16
#define K_  1024   // N_*D_

using short8 = __attribute__((ext_vector_type(8))) short;
using f32x16 = __attribute__((ext_vector_type(16))) float;

#if __has_builtin(__builtin_amdgcn_cvt_pk_u8_f32)
#define CVTPK_U8(f, sel, old) (unsigned)__builtin_amdgcn_cvt_pk_u8_f32((f), (sel), (old))
#else
__device__ __forceinline__ unsigned cvtpk_u8_sw(float f, unsigned sel, unsigned old) {
  unsigned b = (unsigned)(int)f & 0xffu;
  unsigned sh = sel * 8u;
  return (old & ~(0xffu << sh)) | (b << sh);
}
#define CVTPK_U8(f, sel, old) cvtpk_u8_sw((f), (sel), (old))
#endif

__device__ __forceinline__ short8 pack_bf16x8(float a0, float a1, float a2, float a3,
                                              float a4, float a5, float a6, float a7) {
  __hip_bfloat162 p0 = __float22bfloat162_rn(float2{a0, a1});
  __hip_bfloat162 p1 = __float22bfloat162_rn(float2{a2, a3});
  __hip_bfloat162 p2 = __float22bfloat162_rn(float2{a4, a5});
  __hip_bfloat162 p3 = __float22bfloat162_rn(float2{a6, a7});
  union { unsigned u[4]; short8 s; } cv;
  cv.u[0] = *(unsigned*)&p0; cv.u[1] = *(unsigned*)&p1;
  cv.u[2] = *(unsigned*)&p2; cv.u[3] = *(unsigned*)&p3;
  return cv.s;
}

// ---------- projection via MFMA 32x32x16, ONE k-quarter per block ----------
// Grid 8192: block = (i = bid>>2, ph = bid&3). Per block: merged x+W stage,
// ONE barrier, 4 MFMA+quant per wave, barrier, coalesced flush. (Round-15's
// 4-phase loop flattened into the grid: 12 barriers/block -> 3, 4x blocks.)
//   A frag: lane l = A[row=l&31][kappa=(l>>5)*8+e] -> W[j=kappa][k]
//   B frag: lane l = B[kappa=(l>>5)*8+e][col=l&31] -> x[b=col(+32)][j=kappa]
//   D frag: col=l&31 (b), row=(reg&3)+8*(reg>>2)+4*(l>>5)  [m74/m101-verified]
__global__ __launch_bounds__(256) void project_k(const float* __restrict__ x,
                                                 const float* __restrict__ W,
                                                 unsigned char* __restrict__ uh,
                                                 unsigned short* __restrict__ sc) {
  const int i  = blockIdx.x >> 2;
  const int ph = blockIdx.x & 3;
  const int t  = threadIdx.x;
  const int l  = t & 63;
  const int wv = t >> 6;
  const int h  = l >> 5;        // kappa half / d-offset selector
  const int lr = l & 31;        // row (A) / col (B,D)

  __shared__ unsigned short lds_w[256 * 20];   // 10 KB  [k_local][j] pad 20
  __shared__ float          lds_x[64 * 20];    // 5 KB   [b][j] pad 20
  __shared__ unsigned int   out_lds[64 * 64];  // 16 KB  [b][64 dwords] swizzled
  __shared__ unsigned short sc_lds[64 * 20];   // 2.5 KB [b][16] pad 20

  // stage x rows for all 64 b
  {
    int b = t >> 2, q = t & 3;
    float4 v = ((const float4*)(x + ((size_t)b * I_ + i) * J_))[q];
    *(float4*)&lds_x[b * 20 + q * 4] = v;
  }
  // stage W[j][ph*256 + k] -> lds_w[k_local][j] bf16 (4x float4 + 4x4 transpose)
  {
    const float* wp = W + (size_t)i * (J_ * K_) + ph * 256;
    const int j0 = (t & 3) * 4;
    const int kg = t >> 2;               // k_local = kg*4..kg*4+3
    float4 r0 = *(const float4*)(wp + (size_t)(j0 + 0) * K_ + kg * 4);
    float4 r1 = *(const float4*)(wp + (size_t)(j0 + 1) * K_ + kg * 4);
    float4 r2 = *(const float4*)(wp + (size_t)(j0 + 2) * K_ + kg * 4);
    float4 r3 = *(const float4*)(wp + (size_t)(j0 + 3) * K_ + kg * 4);
    const float* p0 = (const float*)&r0;
    const float* p1 = (const float*)&r1;
    const float* p2 = (const float*)&r2;
    const float* p3 = (const float*)&r3;
#pragma unroll
    for (int kk = 0; kk < 4; ++kk) {
      __hip_bfloat162 pA = __float22bfloat162_rn(float2{p0[kk], p1[kk]});
      __hip_bfloat162 pB = __float22bfloat162_rn(float2{p2[kk], p3[kk]});
      uint2 u; u.x = *(unsigned*)&pA; u.y = *(unsigned*)&pB;
      *(uint2*)&lds_w[(kg * 4 + kk) * 20 + j0] = u;
    }
  }
  __syncthreads();

  // B-frag: b = (wv&1)*32 + lr, j = h*8+e
  short8 xfrag;
  {
    int b = (wv & 1) * 32 + lr;
    const float* xp = &lds_x[b * 20 + h * 8];
    float4 f0 = *(const float4*)xp;
    float4 f1 = *(const float4*)(xp + 4);
    xfrag = pack_bf16x8(f0.x, f0.y, f0.z, f0.w, f1.x, f1.y, f1.z, f1.w);
  }

  const int b  = (wv & 1) * 32 + lr;       // D column owned by this lane
  const unsigned sw = (unsigned)((b & 7) << 2);
  const int kt_base = (wv >> 1) * 4;

#pragma unroll
  for (int kk = 0; kk < 4; ++kk) {
    const int kt = kt_base + kk;           // 0..7 (k-tile of 32 within quarter)
    const unsigned short* ap = &lds_w[(kt * 32 + lr) * 20 + h * 8];
    union { uint2 u2[2]; short8 s; } cv;
    cv.u2[0] = *(const uint2*)ap;
    cv.u2[1] = *(const uint2*)(ap + 4);
    f32x16 acc = {0.f, 0.f, 0.f, 0.f, 0.f, 0.f, 0.f, 0.f,
                  0.f, 0.f, 0.f, 0.f, 0.f, 0.f, 0.f, 0.f};
    acc = __builtin_amdgcn_mfma_f32_32x32x16_bf16(cv.s, xfrag, acc, 0, 0, 0);

#define QCAP(C8, CS) do {                                                       \
    float ax = fabsf(acc[(C8) + 0]);                                            \
    ax = fmaxf(ax, fabsf(acc[(C8) + 1]));                                       \
    ax = fmaxf(ax, fabsf(acc[(C8) + 2]));                                       \
    ax = fmaxf(ax, fabsf(acc[(C8) + 3]));                                       \
    ax = fmaxf(ax, fabsf(acc[(C8) + 4]));                                       \
    ax = fmaxf(ax, fabsf(acc[(C8) + 5]));                                       \
    ax = fmaxf(ax, fabsf(acc[(C8) + 6]));                                       \
    ax = fmaxf(ax, fabsf(acc[(C8) + 7]));                                       \
    ax = fmaxf(ax, __shfl_xor(ax, 32));                                         \
    float inv = __fdividef(127.0f, fmaxf(ax, 1e-30f));                          \
    unsigned pk0 = CVTPK_U8(rintf(fmaf(acc[(C8) + 0], inv, 128.f)), 0u, 0u);    \
    pk0 = CVTPK_U8(rintf(fmaf(acc[(C8) + 1], inv, 128.f)), 1u, pk0);            \
    pk0 = CVTPK_U8(rintf(fmaf(acc[(C8) + 2], inv, 128.f)), 2u, pk0);            \
    pk0 = CVTPK_U8(rintf(fmaf(acc[(C8) + 3], inv, 128.f)), 3u, pk0);            \
    unsigned pk1 = CVTPK_U8(rintf(fmaf(acc[(C8) + 4], inv, 128.f)), 0u, 0u);    \
    pk1 = CVTPK_U8(rintf(fmaf(acc[(C8) + 5], inv, 128.f)), 1u, pk1);            \
    pk1 = CVTPK_U8(rintf(fmaf(acc[(C8) + 6], inv, 128.f)), 2u, pk1);            \
    pk1 = CVTPK_U8(rintf(fmaf(acc[(C8) + 7], inv, 128.f)), 3u, pk1);            \
    const int ibase = kt * 8 + (CS) * 4;                                        \
    out_lds[b * 64 + ((unsigned)(ibase + h)     ^ sw)] = pk0;                   \
    out_lds[b * 64 + ((unsigned)(ibase + 2 + h) ^ sw)] = pk1;                   \
    if (h == 0)                                                                 \
      sc_lds[b * 20 + kt * 2 + (CS)] =                                          \
          __half_as_ushort(__float2half_rn(ax * (1.0f / 127.0f)));              \
  } while (0)

    QCAP(0, 0);
    QCAP(8, 1);
#undef QCAP
  }
  __syncthreads();

  // flush u8 data (coalesced 16B/lane) + scales
  {
    const int c = t & 15;
#pragma unroll
    for (int it = 0; it < 4; ++it) {
      int bf = (t >> 4) + it * 16;
      uint4 v = *(const uint4*)&out_lds[bf * 64 + (((unsigned)(c * 4)) ^ ((unsigned)((bf & 7) << 2)))];
      *(uint4*)(uh + (size_t)bf * I_ * K_ + (size_t)i * K_ + ph * 256 + c * 16) = v;
    }
    int b2 = t >> 2, n4 = (t & 3) * 4;
    uint2 sv = *(const uint2*)&sc_lds[b2 * 20 + n4];
    *(uint2*)(sc + (size_t)b2 * I_ * N_ + (size_t)i * N_ + ph * 16 + n4) = sv;
  }
}

// ---------- routing on u8 u_hat (e = q+128): lane = n; 16 B data + 2 B scale ----------
// (unchanged — proven ~18 us each, L3-resident)
template <int MODE>
__global__ __launch_bounds__(256, 4) void route_k(const unsigned char* __restrict__ uh,
                                                  const unsigned short* __restrict__ sc,
                                                  const float* __restrict__ sa,
                                                  const float* __restrict__ sb,
                                                  const float* __restrict__ bias,
                                                  float* __restrict__ s_out) {
  const int t    = threadIdx.x;
  const int lane = t & 63;            // = n
  const int wv   = t >> 6;            // 0..3
  const int b    = blockIdx.x >> 4;
  const int iw   = ((blockIdx.x & 15) << 2) + wv;
  const int i0   = iw * 32;

  float vsum[16];
  float voff = 0.f;
  if (MODE >= 1) {
    float bs[16];
#pragma unroll
    for (int q = 0; q < 4; ++q) {
      float4 bb4 = *(const float4*)&bias[lane * 16 + q * 4];
      bs[q*4+0] = bb4.x; bs[q*4+1] = bb4.y; bs[q*4+2] = bb4.z; bs[q*4+3] = bb4.w;
    }
    {
      float va[16], nn = 0.f;
#pragma unroll
      for (int q = 0; q < 4; ++q) {
        float4 tmp = *(const float4*)&sa[(size_t)b * K_ + lane * 16 + q * 4];
        va[q*4+0] = tmp.x + bs[q*4+0]; va[q*4+1] = tmp.y + bs[q*4+1];
        va[q*4+2] = tmp.z + bs[q*4+2]; va[q*4+3] = tmp.w + bs[q*4+3];
      }
#pragma unroll
      for (int d = 0; d < 16; ++d) nn += va[d] * va[d];
      float n2 = nn + 1e-7f;
      float f = sqrtf(n2) / (1.0f + n2);
#pragma unroll
      for (int d = 0; d < 16; ++d) vsum[d] = va[d] * f;
    }
    if (MODE == 2) {
      float vb[16], nn = 0.f;
#pragma unroll
      for (int q = 0; q < 4; ++q) {
        float4 tmp = *(const float4*)&sb[(size_t)b * K_ + lane * 16 + q * 4];
        vb[q*4+0] = tmp.x + bs[q*4+0]; vb[q*4+1] = tmp.y + bs[q*4+1];
        vb[q*4+2] = tmp.z + bs[q*4+2]; vb[q*4+3] = tmp.w + bs[q*4+3];
      }
#pragma unroll
      for (int d = 0; d < 16; ++d) nn += vb[d] * vb[d];
      float n2 = nn + 1e-7f;
      float f = sqrtf(n2) / (1.0f + n2);
#pragma unroll
      for (int d = 0; d < 16; ++d) vsum[d] += vb[d] * f;
    }
    float tv = 0.f;
#pragma unroll
    for (int d = 0; d < 16; ++d) tv += vsum[d];
    voff = 128.0f * tv;
  }

  constexpr int IPW = 32;
  constexpr int PF  = 4;

  const unsigned char*  base = uh + (size_t)b * I_ * K_ + lane * 16;
  const unsigned short* scb  = sc + (size_t)b * I_ * N_ + lane;

  uint4 dbuf[PF];
  unsigned short hbuf[PF];
#pragma unroll
  for (int p = 0; p < PF; ++p) {
    int ip = (i0 + p) & (I_ - 1);
    dbuf[p] = *(const uint4*)(base + (size_t)ip * K_);
    hbuf[p] = scb[(size_t)ip * N_];
  }

  float s_loc[16];
#pragma unroll
  for (int d = 0; d < 16; ++d) s_loc[d] = 0.f;
  float csum = 0.f;

  for (int ii = 0; ii < IPW; ii += PF) {
#pragma unroll
    for (int p = 0; p < PF; ++p) {
      float scale = __half2float(__ushort_as_half(hbuf[p]));
      float u[16];
      {
        unsigned wd;
        wd = dbuf[p].x;
        u[0]  = (float)(wd & 0xffu);         u[1]  = (float)((wd >> 8) & 0xffu);
        u[2]  = (float)((wd >> 16) & 0xffu); u[3]  = (float)(wd >> 24);
        wd = dbuf[p].y;
        u[4]  = (float)(wd & 0xffu);         u[5]  = (float)((wd >> 8) & 0xffu);
        u[6]  = (float)((wd >> 16) & 0xffu); u[7]  = (float)(wd >> 24);
        wd = dbuf[p].z;
        u[8]  = (float)(wd & 0xffu);         u[9]  = (float)((wd >> 8) & 0xffu);
        u[10] = (float)((wd >> 16) & 0xffu); u[11] = (float)(wd >> 24);
        wd = dbuf[p].w;
        u[12] = (float)(wd & 0xffu);         u[13] = (float)((wd >> 8) & 0xffu);
        u[14] = (float)((wd >> 16) & 0xffu); u[15] = (float)(wd >> 24);
      }

      int ip = (i0 + ii + p + PF) & (I_ - 1);
      dbuf[p] = *(const uint4*)(base + (size_t)ip * K_);
      hbuf[p] = scb[(size_t)ip * N_];

      if (MODE == 0) {
#pragma unroll
        for (int d = 0; d < 16; ++d) s_loc[d] = fmaf(scale, u[d], s_loc[d]);
        csum += scale;
      } else {
        float dot = 0.f;
#pragma unroll
        for (int d = 0; d < 16; ++d) dot = fmaf(u[d], vsum[d], dot);
        float bl = scale * (dot - voff);
        float m = bl;
        m = fmaxf(m, __shfl_xor(m, 1));
        m = fmaxf(m, __shfl_xor(m, 2));
        m = fmaxf(m, __shfl_xor(m, 4));
        m = fmaxf(m, __shfl_xor(m, 8));
        m = fmaxf(m, __shfl_xor(m, 16));
        m = fmaxf(m, __shfl_xor(m, 32));
        float e = __expf(bl - m);
        float ss = e;
        ss += __shfl_xor(ss, 1);
        ss += __shfl_xor(ss, 2);
        ss += __shfl_xor(ss, 4);
        ss += __shfl_xor(ss, 8);
        ss += __shfl_xor(ss, 16);
        ss += __shfl_xor(ss, 32);
        float cs = __fdividef(e, ss) * scale;
#pragma unroll
        for (int d = 0; d < 16; ++d) s_loc[d] = fmaf(cs, u[d], s_loc[d]);
        csum += cs;
      }
    }
  }

#pragma unroll
  for (int d = 0; d < 16; ++d) s_loc[d] -= 128.0f * csum;
  if (MODE == 0) {
#pragma unroll
    for (int d = 0; d < 16; ++d) s_loc[d] *= (1.0f / 64.0f);
  }

  __shared__ float sred[4][64 * 17];
#pragma unroll
  for (int d = 0; d < 16; ++d) sred[wv][lane * 17 + d] = s_loc[d];
  __syncthreads();
#pragma unroll
  for (int e = 0; e < 4; ++e) {
    int idx = t * 4 + e;
    int n = idx >> 4, d = idx & 15;
    float val = sred[0][n*17+d] + sred[1][n*17+d] + sred[2][n*17+d] + sred[3][n*17+d];
    atomicAdd(&s_out[(size_t)b * K_ + idx], val);
  }
}

// ---------- final squash ----------
__global__ __launch_bounds__(256) void squash_k(const float* __restrict__ s_in,
                                                const float* __restrict__ bias,
                                                float* __restrict__ v_out) {
  const int b = blockIdx.x, t = threadIdx.x, k0 = t * 4;
  float4 s = *(const float4*)&s_in[b * K_ + k0];
  float4 bb = *(const float4*)&bias[k0];
  s.x += bb.x; s.y += bb.y; s.z += bb.z; s.w += bb.w;
  float p = s.x * s.x + s.y * s.y + s.z * s.z + s.w * s.w;
  p += __shfl_xor(p, 1);
  p += __shfl_xor(p, 2);
  float n2 = p + 1e-7f;
  float nrm = sqrtf(n2);
  float f = nrm / (1.0f + n2);
  float4 o = {s.x * f, s.y * f, s.z * f, s.w * f};
  *(float4*)&v_out[b * K_ + k0] = o;
}

extern "C" void kernel_launch(void* const* d_in, const int* in_sizes, int n_in,
                              void* d_out, int out_size, void* d_ws, size_t ws_size,
                              hipStream_t stream) {
  const float* x    = (const float*)d_in[0];
  const float* W    = (const float*)d_in[1];
  const float* bias = (const float*)d_in[2];
  float* out = (float*)d_out;

  char* ws = (char*)d_ws;
  size_t off = 0;
  unsigned char*  uh = (unsigned char*)(ws + off);  off += (size_t)B_ * I_ * K_;      // 134 MB u8
  unsigned short* sc = (unsigned short*)(ws + off); off += (size_t)B_ * I_ * N_ * 2;  // 16.8 MB f16 scales
  float* s0 = (float*)(ws + off); off += (size_t)B_ * K_ * 4;
  float* s1 = (float*)(ws + off); off += (size_t)B_ * K_ * 4;
  float* s2 = (float*)(ws + off); off += (size_t)B_ * K_ * 4;

  if (ws_size < off)
    fprintf(stderr, "ClassCapsule: ws_size=%zu < needed=%zu — expect corruption\n", ws_size, off);

  (void)hipMemsetAsync(s0, 0, (size_t)3 * B_ * K_ * 4, stream);  // s0,s1,s2 contiguous

  project_k<<<dim3(I_ * 4), dim3(256), 0, stream>>>(x, W, uh, sc);

  route_k<0><<<dim3(1024), dim3(256), 0, stream>>>(uh, sc, nullptr, nullptr, bias, s0);
  route_k<1><<<dim3(1024), dim3(256), 0, stream>>>(uh, sc, s0, nullptr, bias, s1);
  route_k<2><<<dim3(1024), dim3(256), 0, stream>>>(uh, sc, s0, s1, bias, s2);
  squash_k<<<dim3(B_), dim3(256), 0, stream>>>(s2, bias, out);
}